// Round 14
// baseline (260.874 us; speedup 1.0000x reference)
//
#include <hip/hip_runtime.h>
#include <math.h>

// FactorizedSpectralConv2d: pruned-DFT + TT contraction, MFMA everywhere matmul-shaped.
//
//   k_prepTables: split-bf16 A-frag tables FH/IH + FW B-frags + invW E B-frags + a A-frags
//   k_prepBG    : bf16 frag tables for b (A) and g (B); g computed inline (sum_k c*d)
//   k_stage1m   : W-DFT of x via MFMA -> Yt 4 bf16 planes [h/8][p][8] (LDS-staged twiddles)
//   k_cmfma     : XF[k][p] = sum_h FH[k][h] Yt[h][p]    (split-bf16 complex MFMA)
//   k_contractA : MFMA w-GEMM + fp32 t-update; t written as bf16-HI frag planes tA (2 planes)
//   k_amfma     : OF[o,(k,b,m)] = sum_i a[o,i] tA[i,(k,b,m)]  (a split, t hi-only; 8 MFMAs)
//   k_ihinv     : FUSED per-bo block: phase1 Z = IH·OF (OF split on the fly, Z -> LDS bf16-hi
//                 XOR-swizzled); phase2 out = Re(Z . E) via MFMA from LDS.

#define TWO_PI 6.28318530717958647692f

typedef __attribute__((ext_vector_type(8))) short short8v;   // 8 bf16 (4 VGPRs)
typedef __attribute__((ext_vector_type(4))) float float4v;   // MFMA C/D

namespace {
constexpr size_t P_ = 32768;            // B*C*KW pixel batch width

// workspace float offsets
constexpr size_t oYT = 0;                     // Yt: 4 planes [32][32768][8] bf16 = 16.77M floats
                                              //   then bA/gB + tA (contract)
constexpr size_t oTA = 1048576;               // tA: 2 planes [8][32768][8] bf16
constexpr size_t oXF = 16777216;              // XF f2 33.5MB
constexpr size_t oOF = 25165824;              // OF f2 33.5MB (read by k_ihinv)
constexpr size_t oBF = 33554432;              // FW B-frag table: 65536 shorts
constexpr size_t oAF1 = 33587200;             // FH frags: 196608 shorts
constexpr size_t oAF2 = 33685504;             // IH frags: 196608 shorts
constexpr size_t oG  = 33792000;              // AFa (98304 shorts) then EF (32768 shorts)
constexpr size_t oEF = oG + 262144;
constexpr size_t WS_FLOATS = oG + 524288;     // ~137.3 MB
}

__device__ __forceinline__ unsigned short f2bf(float f) {   // RNE float->bf16 bits
    unsigned int u = __float_as_uint(f);
    unsigned int r = (u + 0x7FFFu + ((u >> 16) & 1u)) >> 16;
    return (unsigned short)r;
}
__device__ __forceinline__ float bf2f(unsigned short b) {
    return __uint_as_float(((unsigned int)b) << 16);
}

// All static fragment tables in one launch:
//   [0, 393216)            AF1 (FH) / AF2 (IH) split-bf16 A-frags
//   [393216, 458752)       BF: FW B-frags (4 planes ch,cl,sh,sl)
//   [458752, 491520)       EF: invW twiddle B-frags (2 planes Er, -Ei; bf16-hi, scaled)
//   [491520, 589824)       AFa: a1/a2 split-bf16 A-frags
__global__ __launch_bounds__(256) void k_prepTables(const float* __restrict__ a1,
                                                    const float* __restrict__ a2,
                                                    unsigned short* __restrict__ AF1,
                                                    unsigned short* __restrict__ AF2,
                                                    unsigned short* __restrict__ BF,
                                                    unsigned short* __restrict__ EF,
                                                    unsigned short* __restrict__ AFa) {
    int idx = blockIdx.x * 256 + threadIdx.x;      // < 589824
    if (idx < 393216) {
        int tbl = (idx >= 196608);
        int id = tbl ? (idx - 196608) : idx;
        int e = id & 7, lane = (id >> 3) & 63;
        int pl = id >> 15;
        float ang;
        if (!tbl) {
            int rt = (id >> 9) & 7, kc = (id >> 12) & 7;
            int r = rt * 16 + (lane & 15);             // k-row (128)
            int s = kc * 32 + 8 * (lane >> 4) + e;     // h (256)
            int kh = r + ((r >= 64) ? 128 : 0);
            int ph = (kh * s) & 255;
            ang = -TWO_PI * (float)ph / 256.0f;
        } else {
            int rt = (id >> 9) & 15, kc = (id >> 13) & 3;
            int r = rt * 16 + (lane & 15);             // h (256)
            int s = kc * 32 + 8 * (lane >> 4) + e;     // k (128)
            int kh = s + ((s >= 64) ? 128 : 0);
            int ph = (kh * r) & 255;
            ang = TWO_PI * (float)ph / 256.0f;
        }
        float sn, cs; sincosf(ang, &sn, &cs);
        float base = (pl < 2) ? cs : ((pl < 4) ? sn : -sn);
        unsigned short hi = f2bf(base);
        unsigned short out = (pl & 1) ? f2bf(base - bf2f(hi)) : hi;
        (tbl ? AF2 : AF1)[id] = out;
    } else if (idx < 458752) {
        int id = idx - 393216;                          // < 65536
        int e = id & 7, lane = (id >> 3) & 63;
        int nt = (id >> 9) & 3, kc = (id >> 11) & 7;
        int pl = id >> 14;                              // 0..3
        int kw = nt * 16 + (lane & 15);
        int w = kc * 32 + 8 * (lane >> 4) + e;
        int ph = (w * kw) & 255;
        float ang = -TWO_PI * (float)ph / 256.0f;
        float sn, cs; sincosf(ang, &sn, &cs);
        float base = (pl < 2) ? cs : sn;
        unsigned short hi = f2bf(base);
        unsigned short out = (pl & 1) ? f2bf(base - bf2f(hi)) : hi;
        BF[id] = out;
    } else if (idx < 491520) {
        int id = idx - 458752;                          // < 32768
        int e = id & 7, lane = (id >> 3) & 63;
        int nt = (id >> 9) & 15, kc = (id >> 13) & 1, pl = id >> 14;
        int w = nt * 16 + (lane & 15);
        int kw = kc * 32 + 8 * (lane >> 4) + e;
        int ph = (kw * w) & 255;
        float ang = TWO_PI * (float)ph / 256.0f;
        float sn, cs; sincosf(ang, &sn, &cs);
        float sc = ((kw == 0) ? 1.0f : 2.0f) / 65536.0f;
        float v = (pl == 0) ? (sc * cs) : (-sc * sn);
        EF[id] = f2bf(v);
    } else {
        int id = idx - 491520;                          // < 98304
        int e = id & 7, lane = (id >> 3) & 63;
        int rt = (id >> 9) & 7, kc = (id >> 12) & 1;
        int plreg = id >> 13;                           // 0..11
        int reg = plreg / 6, pl = plreg % 6;
        int o = rt * 16 + (lane & 15);
        int i = kc * 32 + 8 * (lane >> 4) + e;
        const float* ap = reg ? a2 : a1;
        float ar = ap[(o * 64 + i) * 2 + 0];
        float ai = ap[(o * 64 + i) * 2 + 1];
        float base = (pl < 2) ? ar : ((pl < 4) ? ai : -ai);
        unsigned short hi = f2bf(base);
        unsigned short out = (pl & 1) ? f2bf(base - bf2f(hi)) : hi;
        AFa[id] = out;
    }
}

// bf16 fragment tables for the contraction; g computed inline (sum_k c*d).
__global__ __launch_bounds__(256) void k_prepBG(const float* __restrict__ b1, const float* __restrict__ b2,
                                                const float* __restrict__ c1, const float* __restrict__ d1,
                                                const float* __restrict__ c2, const float* __restrict__ d2,
                                                unsigned short* __restrict__ bA,
                                                unsigned short* __restrict__ gB) {
    size_t idx = (size_t)blockIdx.x * 256 + threadIdx.x;
    if (idx < 1048576) {
        int e     = idx & 7;
        int lane  = (idx >> 3) & 63;
        int c     = (idx >> 9) & 127;
        int itile = (idx >> 16) & 3;
        int reg   = (idx >> 18) & 1;
        int plane = (idx >> 19) & 1;
        int i = itile * 16 + (lane & 15);
        int j = 8 * (lane >> 4) + e;
        const float* bp = reg ? b2 : b1;
        float v = bp[((size_t)(i * 128 + c) * 32 + j) * 2 + plane];
        bA[idx] = f2bf(v);
    } else if (idx < 1048576 + 786432) {
        size_t i2 = idx - 1048576;
        int e     = i2 & 7;
        int lane  = (i2 >> 3) & 63;
        int ytile = (i2 >> 9) & 3;
        int xm    = (i2 >> 11) & 63;
        int reg   = (i2 >> 17) & 1;
        int plane = (int)(i2 >> 18);           // 0,1,2
        int y = ytile * 16 + (lane & 15);
        int j = 8 * (lane >> 4) + e;
        const float* cp = reg ? c2 : c1;
        const float* dp = reg ? d2 : d1;
        float sr = 0.f, si = 0.f;
        for (int kk = 0; kk < 32; ++kk) {
            float cr = cp[((j * 64 + xm) * 32 + kk) * 2 + 0];
            float ci = cp[((j * 64 + xm) * 32 + kk) * 2 + 1];
            float dr = dp[(kk * 64 + y) * 2 + 0];
            float di = dp[(kk * 64 + y) * 2 + 1];
            sr = fmaf(cr, dr, fmaf(-ci, di, sr));
            si = fmaf(cr, di, fmaf( ci, dr, si));
        }
        float v = (plane == 0) ? sr : ((plane == 1) ? si : -si);
        gB[i2] = f2bf(v);
    }
}

// MFMA W-DFT v4: BF staged via LDS in 32KB barrier-synced phases (2 kc each).
__global__ __launch_bounds__(256) void k_stage1m(const float* __restrict__ x,
                                                 const unsigned short* __restrict__ BF,
                                                 unsigned short* __restrict__ Yt) {
    __shared__ __align__(16) unsigned short es[16384];   // 32 KB
    int t = threadIdx.x;
    int wave = t >> 6, lane = t & 63;
    size_t row0 = (size_t)blockIdx.x * 128 + (size_t)wave * 32;
    int colp = lane & 15, rowq = lane >> 4;
    const short8v* esv = (const short8v*)es;

    float4v accR[2][4], accI[2][4];
#pragma unroll
    for (int rt = 0; rt < 2; ++rt)
#pragma unroll
        for (int nt = 0; nt < 4; ++nt) {
            accR[rt][nt] = (float4v){0.f, 0.f, 0.f, 0.f};
            accI[rt][nt] = (float4v){0.f, 0.f, 0.f, 0.f};
        }

    const float* xb0 = x + (row0 + colp) * 256 + 8 * rowq;
    const float* xb1 = xb0 + 16 * 256;
    float4 nv[2][2];
    nv[0][0] = *(const float4*)(xb0);  nv[0][1] = *(const float4*)(xb0 + 4);
    nv[1][0] = *(const float4*)(xb1);  nv[1][1] = *(const float4*)(xb1 + 4);

    const float4* bf4 = (const float4*)BF;
    for (int ph = 0; ph < 4; ++ph) {
        __syncthreads();
        {
#pragma unroll
            for (int i = 0; i < 8; ++i) {
                int idx = t + 256 * i;
                int li  = idx & 63;
                int nt  = (idx >> 6) & 3;
                int kcl = (idx >> 8) & 1;
                int pl  = idx >> 9;
                ((float4*)es)[idx] = bf4[((size_t)(pl * 8 + ph * 2 + kcl) * 4 + nt) * 64 + li];
            }
        }
        __syncthreads();
        for (int kcl = 0; kcl < 2; ++kcl) {
            int kc = ph * 2 + kcl;
            short8v xh[2];
#pragma unroll
            for (int rt = 0; rt < 2; ++rt) {
                float4 v0 = nv[rt][0], v1 = nv[rt][1];
                float vv[8] = {v0.x, v0.y, v0.z, v0.w, v1.x, v1.y, v1.z, v1.w};
#pragma unroll
                for (int j = 0; j < 8; ++j) xh[rt][j] = (short)f2bf(vv[j]);
            }
            if (kc < 7) {
                nv[0][0] = *(const float4*)(xb0 + (kc + 1) * 32);
                nv[0][1] = *(const float4*)(xb0 + (kc + 1) * 32 + 4);
                nv[1][0] = *(const float4*)(xb1 + (kc + 1) * 32);
                nv[1][1] = *(const float4*)(xb1 + (kc + 1) * 32 + 4);
            }
#pragma unroll
            for (int nt = 0; nt < 4; ++nt) {
                short8v Bch = esv[((0 * 2 + kcl) * 4 + nt) * 64 + lane];
                short8v Bcl = esv[((1 * 2 + kcl) * 4 + nt) * 64 + lane];
                short8v Bsh = esv[((2 * 2 + kcl) * 4 + nt) * 64 + lane];
                short8v Bsl = esv[((3 * 2 + kcl) * 4 + nt) * 64 + lane];
#pragma unroll
                for (int rt = 0; rt < 2; ++rt) {
                    float4v r_ = accR[rt][nt];
                    r_ = __builtin_amdgcn_mfma_f32_16x16x32_bf16(xh[rt], Bch, r_, 0, 0, 0);
                    r_ = __builtin_amdgcn_mfma_f32_16x16x32_bf16(xh[rt], Bcl, r_, 0, 0, 0);
                    accR[rt][nt] = r_;
                    float4v i_ = accI[rt][nt];
                    i_ = __builtin_amdgcn_mfma_f32_16x16x32_bf16(xh[rt], Bsh, i_, 0, 0, 0);
                    i_ = __builtin_amdgcn_mfma_f32_16x16x32_bf16(xh[rt], Bsl, i_, 0, 0, 0);
                    accI[rt][nt] = i_;
                }
            }
        }
    }

    short* Yts = (short*)Yt;
    const size_t PLY = (size_t)32 * 32768 * 8;
#pragma unroll
    for (int rt = 0; rt < 2; ++rt) {
        size_t xrow0 = row0 + rt * 16 + rowq * 4;
        int h = (int)(xrow0 & 255), bc = (int)(xrow0 >> 8);
        size_t gbase = (size_t)(h >> 3) * 32768;
        int e0 = h & 7;
#pragma unroll
        for (int nt = 0; nt < 4; ++nt) {
            size_t p = (size_t)bc * 64 + nt * 16 + colp;
            size_t off = (gbase + p) * 8 + e0;
            float4v R = accR[rt][nt], I = accI[rt][nt];
            short rh[4], rl[4], ih[4], il[4];
#pragma unroll
            for (int q = 0; q < 4; ++q) {
                unsigned short h1 = f2bf(R[q]);
                rh[q] = (short)h1; rl[q] = (short)f2bf(R[q] - bf2f(h1));
                unsigned short h2 = f2bf(I[q]);
                ih[q] = (short)h2; il[q] = (short)f2bf(I[q] - bf2f(h2));
            }
            *(short4*)&Yts[0 * PLY + off] = make_short4(rh[0], rh[1], rh[2], rh[3]);
            *(short4*)&Yts[1 * PLY + off] = make_short4(rl[0], rl[1], rl[2], rl[3]);
            *(short4*)&Yts[2 * PLY + off] = make_short4(ih[0], ih[1], ih[2], ih[3]);
            *(short4*)&Yts[3 * PLY + off] = make_short4(il[0], il[1], il[2], il[3]);
        }
    }
}

// Split-bf16 complex MFMA GEMM (FH: Yt -> XF).
template<int S, int RT_W>
__global__ __launch_bounds__(256) void k_cmfma(const unsigned short* __restrict__ AF,
                                               const unsigned short* __restrict__ Bt,
                                               float2* __restrict__ Out) {
    constexpr int KC = S / 32;
    constexpr int SG = S / 8;
    constexpr int RTOT = RT_W * 4;
    __shared__ __align__(16) unsigned short bs[4 * SG * 16 * 8];
    int t = threadIdx.x;
    int wave = t >> 6, lane = t & 63;
    int rt0 = wave * RT_W;
    int colp = lane & 15, rowq = lane >> 4;
    const short8v* AFv = (const short8v*)AF;
    const short8v* bsv = (const short8v*)bs;
    const size_t PLA = (size_t)KC * RTOT * 64;

    for (int pt = 0; pt < 4; ++pt) {
        int p0 = blockIdx.x * 64 + pt * 16;
        __syncthreads();
        {
            const float4* src = (const float4*)Bt;
            float4* dst = (float4*)bs;
            for (int e = t; e < 4 * SG * 16; e += 256) {
                int pl = e / (SG * 16); int rem = e - pl * (SG * 16);
                int g = rem >> 4, li = rem & 15;
                dst[e] = src[((size_t)pl * SG + g) * 32768 + p0 + li];
            }
        }
        __syncthreads();
        float4v accR[RT_W], accI[RT_W];
#pragma unroll
        for (int rt = 0; rt < RT_W; ++rt) {
            accR[rt] = (float4v){0.f, 0.f, 0.f, 0.f};
            accI[rt] = (float4v){0.f, 0.f, 0.f, 0.f};
        }
#pragma unroll
        for (int kc = 0; kc < KC; ++kc) {
            int gi = kc * 4 + rowq;
            short8v Brh = bsv[((0 * SG + gi) << 4) + colp];
            short8v Brl = bsv[((1 * SG + gi) << 4) + colp];
            short8v Bih = bsv[((2 * SG + gi) << 4) + colp];
            short8v Bil = bsv[((3 * SG + gi) << 4) + colp];
#pragma unroll
            for (int rt = 0; rt < RT_W; ++rt) {
                size_t ab = ((size_t)kc * RTOT + rt0 + rt) * 64 + lane;
                short8v A0 = AFv[0 * PLA + ab];
                short8v A1 = AFv[1 * PLA + ab];
                short8v A2 = AFv[2 * PLA + ab];
                short8v A3 = AFv[3 * PLA + ab];
                short8v A4 = AFv[4 * PLA + ab];
                short8v A5 = AFv[5 * PLA + ab];
                float4v r_ = accR[rt];
                r_ = __builtin_amdgcn_mfma_f32_16x16x32_bf16(A0, Brh, r_, 0, 0, 0);
                r_ = __builtin_amdgcn_mfma_f32_16x16x32_bf16(A0, Brl, r_, 0, 0, 0);
                r_ = __builtin_amdgcn_mfma_f32_16x16x32_bf16(A1, Brh, r_, 0, 0, 0);
                r_ = __builtin_amdgcn_mfma_f32_16x16x32_bf16(A4, Bih, r_, 0, 0, 0);
                r_ = __builtin_amdgcn_mfma_f32_16x16x32_bf16(A4, Bil, r_, 0, 0, 0);
                r_ = __builtin_amdgcn_mfma_f32_16x16x32_bf16(A5, Bih, r_, 0, 0, 0);
                accR[rt] = r_;
                float4v i_ = accI[rt];
                i_ = __builtin_amdgcn_mfma_f32_16x16x32_bf16(A2, Brh, i_, 0, 0, 0);
                i_ = __builtin_amdgcn_mfma_f32_16x16x32_bf16(A2, Brl, i_, 0, 0, 0);
                i_ = __builtin_amdgcn_mfma_f32_16x16x32_bf16(A3, Brh, i_, 0, 0, 0);
                i_ = __builtin_amdgcn_mfma_f32_16x16x32_bf16(A0, Bih, i_, 0, 0, 0);
                i_ = __builtin_amdgcn_mfma_f32_16x16x32_bf16(A0, Bil, i_, 0, 0, 0);
                i_ = __builtin_amdgcn_mfma_f32_16x16x32_bf16(A1, Bih, i_, 0, 0, 0);
                accI[rt] = i_;
            }
        }
#pragma unroll
        for (int rt = 0; rt < RT_W; ++rt) {
            int rbase = (rt0 + rt) * 16 + rowq * 4;
#pragma unroll
            for (int q = 0; q < 4; ++q)
                Out[(size_t)(rbase + q) * P_ + p0 + colp] = make_float2(accR[rt][q], accI[rt][q]);
        }
    }
}

// MFMA contract, phase A -> tA bf16-HI only (2 planes).
__global__ __launch_bounds__(256) void k_contractA(const float2* __restrict__ XF,
                                                   const unsigned short* __restrict__ bA,
                                                   const unsigned short* __restrict__ gB,
                                                   unsigned short* __restrict__ tA) {
    int t = threadIdx.x;
    int k = blockIdx.x >> 2;
    int ytile = blockIdx.x & 3;
    int y0 = ytile << 4;
    int reg = (k >= 64) ? 1 : 0;
    int x = k & 63;
    int itile = t >> 6, lane = t & 63;
    int ylane = lane & 15, qg = lane >> 4;

    const short8v* gBv = (const short8v*)gB;
    short8v g_r  = gBv[(((size_t)(0 * 2 + reg) * 64 + x) * 4 + ytile) * 64 + lane];
    short8v g_i  = gBv[(((size_t)(1 * 2 + reg) * 64 + x) * 4 + ytile) * 64 + lane];
    short8v g_ni = gBv[(((size_t)(2 * 2 + reg) * 64 + x) * 4 + ytile) * 64 + lane];

    const short8v* bAv = (const short8v*)bA;
    size_t aR = (((size_t)(0 * 2 + reg) * 4 + itile) * 128) * 64 + lane;
    size_t aI = (((size_t)(1 * 2 + reg) * 4 + itile) * 128) * 64 + lane;

    const float2* xfp = XF + (size_t)k * 32768 + y0 + ylane;

    float tr[4][4], ti[4][4];
#pragma unroll
    for (int q = 0; q < 4; ++q)
#pragma unroll
        for (int b = 0; b < 4; ++b) { tr[q][b] = 0.f; ti[q][b] = 0.f; }

#pragma unroll 2
    for (int c = 0; c < 128; ++c) {
        short8v av = bAv[aR + (size_t)c * 64];
        short8v aw = bAv[aI + (size_t)c * 64];
        float4v z4 = {0.f, 0.f, 0.f, 0.f};
        float4v wr = __builtin_amdgcn_mfma_f32_16x16x32_bf16(av, g_r, z4, 0, 0, 0);
        wr = __builtin_amdgcn_mfma_f32_16x16x32_bf16(aw, g_ni, wr, 0, 0, 0);
        float4v wi = __builtin_amdgcn_mfma_f32_16x16x32_bf16(av, g_i, z4, 0, 0, 0);
        wi = __builtin_amdgcn_mfma_f32_16x16x32_bf16(aw, g_r, wi, 0, 0, 0);
#pragma unroll
        for (int b = 0; b < 4; ++b) {
            float2 xv = xfp[(size_t)b * 8192 + (size_t)c * 64];
#pragma unroll
            for (int q = 0; q < 4; ++q) {
                tr[q][b] = fmaf(wr[q], xv.x, fmaf(-wi[q], xv.y, tr[q][b]));
                ti[q][b] = fmaf(wr[q], xv.y, fmaf( wi[q], xv.x, ti[q][b]));
            }
        }
    }

    short* tAs = (short*)tA;
    const size_t PLT = (size_t)8 * 32768 * 8;     // plane stride (shorts)
    int gidx = itile * 2 + (qg >> 1);
    int e0 = (qg & 1) * 4;
#pragma unroll
    for (int b = 0; b < 4; ++b) {
        size_t col = (size_t)k * 256 + (size_t)b * 64 + y0 + ylane;
        size_t off = ((size_t)gidx * 32768 + col) * 8 + e0;
        short rh[4], ih[4];
#pragma unroll
        for (int q = 0; q < 4; ++q) {
            rh[q] = (short)f2bf(tr[q][b]);
            ih[q] = (short)f2bf(ti[q][b]);
        }
        *(short4*)&tAs[0 * PLT + off] = make_short4(rh[0], rh[1], rh[2], rh[3]);
        *(short4*)&tAs[1 * PLT + off] = make_short4(ih[0], ih[1], ih[2], ih[3]);
    }
}

// MFMA contract, phase B -> OF fp32. (a split-bf16, t bf16-hi: 8 MFMAs per (kc,rt))
__global__ __launch_bounds__(256) void k_amfma(const unsigned short* __restrict__ AFa,
                                               const unsigned short* __restrict__ tA,
                                               float2* __restrict__ OF) {
    constexpr int SG = 8;
    __shared__ __align__(16) unsigned short bs[2 * SG * 16 * 8];   // 4 KB
    int t = threadIdx.x;
    int wave = t >> 6, lane = t & 63;
    int rt0 = wave * 2;
    int colp = lane & 15, rowq = lane >> 4;
    int k = blockIdx.x >> 2, b = blockIdx.x & 3;
    int reg = (k >= 64) ? 1 : 0;
    const short8v* AFv = (const short8v*)(AFa + (size_t)reg * 6 * 2 * 8 * 512);
    const size_t PLA = 2 * 8 * 64;
    const short8v* bsv = (const short8v*)bs;
    size_t p0 = (size_t)blockIdx.x * 64;

    for (int pt = 0; pt < 4; ++pt) {
        __syncthreads();
        {   // stage 2 planes x 8 groups x 16 cols = 256 float4 (1/thread)
            const float4* src = (const float4*)tA;
            float4* dst = (float4*)bs;
            int e = t;
            int pl = e >> 7; int rem = e & 127;
            int g = rem >> 4, li = rem & 15;
            dst[e] = src[((size_t)pl * SG + g) * 32768 + p0 + pt * 16 + li];
        }
        __syncthreads();
        float4v accR[2], accI[2];
#pragma unroll
        for (int rt = 0; rt < 2; ++rt) {
            accR[rt] = (float4v){0.f, 0.f, 0.f, 0.f};
            accI[rt] = (float4v){0.f, 0.f, 0.f, 0.f};
        }
#pragma unroll
        for (int kc = 0; kc < 2; ++kc) {
            int gi = kc * 4 + rowq;
            short8v Brh = bsv[((0 * SG + gi) << 4) + colp];
            short8v Bih = bsv[((1 * SG + gi) << 4) + colp];
#pragma unroll
            for (int rt = 0; rt < 2; ++rt) {
                size_t ab = ((size_t)kc * 8 + rt0 + rt) * 64 + lane;
                short8v A0 = AFv[0 * PLA + ab];
                short8v A1 = AFv[1 * PLA + ab];
                short8v A2 = AFv[2 * PLA + ab];
                short8v A3 = AFv[3 * PLA + ab];
                short8v A4 = AFv[4 * PLA + ab];
                short8v A5 = AFv[5 * PLA + ab];
                float4v r_ = accR[rt];
                r_ = __builtin_amdgcn_mfma_f32_16x16x32_bf16(A0, Brh, r_, 0, 0, 0);
                r_ = __builtin_amdgcn_mfma_f32_16x16x32_bf16(A1, Brh, r_, 0, 0, 0);
                r_ = __builtin_amdgcn_mfma_f32_16x16x32_bf16(A4, Bih, r_, 0, 0, 0);
                r_ = __builtin_amdgcn_mfma_f32_16x16x32_bf16(A5, Bih, r_, 0, 0, 0);
                accR[rt] = r_;
                float4v i_ = accI[rt];
                i_ = __builtin_amdgcn_mfma_f32_16x16x32_bf16(A2, Brh, i_, 0, 0, 0);
                i_ = __builtin_amdgcn_mfma_f32_16x16x32_bf16(A3, Brh, i_, 0, 0, 0);
                i_ = __builtin_amdgcn_mfma_f32_16x16x32_bf16(A0, Bih, i_, 0, 0, 0);
                i_ = __builtin_amdgcn_mfma_f32_16x16x32_bf16(A1, Bih, i_, 0, 0, 0);
                accI[rt] = i_;
            }
        }
        int m = pt * 16 + colp;
#pragma unroll
        for (int rt = 0; rt < 2; ++rt) {
            int o0 = (rt0 + rt) * 16 + rowq * 4;
#pragma unroll
            for (int q = 0; q < 4; ++q)
                OF[(size_t)k * 32768 + (size_t)b * 8192 + (size_t)(o0 + q) * 64 + m] =
                    make_float2(accR[rt][q], accI[rt][q]);
        }
    }
}

// FUSED IH-GEMM + inverse-W MFMA. Block = one bo (b*128+o), 512 threads (8 waves).
__global__ __launch_bounds__(512) void k_ihinv(const unsigned short* __restrict__ AF2,
                                               const float2* __restrict__ OF,
                                               const unsigned short* __restrict__ EF,
                                               float* __restrict__ out) {
    constexpr int SG = 16, KC = 4, RTOT = 16;
    __shared__ __align__(16) unsigned short zs[2 * 256 * 64];     // 64 KB
    __shared__ __align__(16) unsigned short bs[4 * SG * 16 * 8];  // 16 KB
    int t = threadIdx.x;
    int wave = t >> 6, lane = t & 63;
    int colp = lane & 15, rowq = lane >> 4;
    int rt0 = wave * 2;
    int bo = blockIdx.x;
    size_t p0 = (size_t)bo * 64;
    const short8v* AFv = (const short8v*)AF2;
    const short8v* bsv = (const short8v*)bs;
    const size_t PLA = (size_t)KC * RTOT * 64;

    for (int pt = 0; pt < 4; ++pt) {
        __syncthreads();
        {   // stage B tile from OF fp32 (split hi/lo): 512 threads x 4 rows each
            int li = t & 15, g = (t >> 4) & 15, half = t >> 8;
            int e0 = half * 4;
            short rh[4], rl[4], ih[4], il[4];
#pragma unroll
            for (int j = 0; j < 4; ++j) {
                float2 v = OF[(size_t)(g * 8 + e0 + j) * P_ + p0 + pt * 16 + li];
                unsigned short h1 = f2bf(v.x);
                rh[j] = (short)h1; rl[j] = (short)f2bf(v.x - bf2f(h1));
                unsigned short h2 = f2bf(v.y);
                ih[j] = (short)h2; il[j] = (short)f2bf(v.y - bf2f(h2));
            }
            int base = (g * 16 + li) * 8 + e0;
            *(short4*)&bs[0 * 2048 + base] = make_short4(rh[0], rh[1], rh[2], rh[3]);
            *(short4*)&bs[1 * 2048 + base] = make_short4(rl[0], rl[1], rl[2], rl[3]);
            *(short4*)&bs[2 * 2048 + base] = make_short4(ih[0], ih[1], ih[2], ih[3]);
            *(short4*)&bs[3 * 2048 + base] = make_short4(il[0], il[1], il[2], il[3]);
        }
        __syncthreads();
        float4v accR[2], accI[2];
#pragma unroll
        for (int rt = 0; rt < 2; ++rt) {
            accR[rt] = (float4v){0.f, 0.f, 0.f, 0.f};
            accI[rt] = (float4v){0.f, 0.f, 0.f, 0.f};
        }
#pragma unroll
        for (int kc = 0; kc < KC; ++kc) {
            int gi = kc * 4 + rowq;
            short8v Brh = bsv[((0 * SG + gi) << 4) + colp];
            short8v Brl = bsv[((1 * SG + gi) << 4) + colp];
            short8v Bih = bsv[((2 * SG + gi) << 4) + colp];
            short8v Bil = bsv[((3 * SG + gi) << 4) + colp];
#pragma unroll
            for (int rt = 0; rt < 2; ++rt) {
                size_t ab = ((size_t)kc * RTOT + rt0 + rt) * 64 + lane;
                short8v A0 = AFv[0 * PLA + ab];
                short8v A1 = AFv[1 * PLA + ab];
                short8v A2 = AFv[2 * PLA + ab];
                short8v A3 = AFv[3 * PLA + ab];
                short8v A4 = AFv[4 * PLA + ab];
                short8v A5 = AFv[5 * PLA + ab];
                float4v r_ = accR[rt];
                r_ = __builtin_amdgcn_mfma_f32_16x16x32_bf16(A0, Brh, r_, 0, 0, 0);
                r_ = __builtin_amdgcn_mfma_f32_16x16x32_bf16(A0, Brl, r_, 0, 0, 0);
                r_ = __builtin_amdgcn_mfma_f32_16x16x32_bf16(A1, Brh, r_, 0, 0, 0);
                r_ = __builtin_amdgcn_mfma_f32_16x16x32_bf16(A4, Bih, r_, 0, 0, 0);
                r_ = __builtin_amdgcn_mfma_f32_16x16x32_bf16(A4, Bil, r_, 0, 0, 0);
                r_ = __builtin_amdgcn_mfma_f32_16x16x32_bf16(A5, Bih, r_, 0, 0, 0);
                accR[rt] = r_;
                float4v i_ = accI[rt];
                i_ = __builtin_amdgcn_mfma_f32_16x16x32_bf16(A2, Brh, i_, 0, 0, 0);
                i_ = __builtin_amdgcn_mfma_f32_16x16x32_bf16(A2, Brl, i_, 0, 0, 0);
                i_ = __builtin_amdgcn_mfma_f32_16x16x32_bf16(A3, Brh, i_, 0, 0, 0);
                i_ = __builtin_amdgcn_mfma_f32_16x16x32_bf16(A0, Bih, i_, 0, 0, 0);
                i_ = __builtin_amdgcn_mfma_f32_16x16x32_bf16(A0, Bil, i_, 0, 0, 0);
                i_ = __builtin_amdgcn_mfma_f32_16x16x32_bf16(A1, Bih, i_, 0, 0, 0);
                accI[rt] = i_;
            }
        }
#pragma unroll
        for (int rt = 0; rt < 2; ++rt)
#pragma unroll
            for (int q = 0; q < 4; ++q) {
                int h = (rt0 + rt) * 16 + rowq * 4 + q;
                int kwsw = (pt * 16 + colp) ^ ((h & 7) << 3);
                zs[h * 64 + kwsw] = (unsigned short)f2bf(accR[rt][q]);
                zs[16384 + h * 64 + kwsw] = (unsigned short)f2bf(accI[rt][q]);
            }
    }
    __syncthreads();

    const short8v* EFv = (const short8v*)EF;
    for (int nt = 0; nt < 16; ++nt) {
        short8v Er0  = EFv[((0 * 2 + 0) * 16 + nt) * 64 + lane];
        short8v Er1  = EFv[((0 * 2 + 1) * 16 + nt) * 64 + lane];
        short8v nEi0 = EFv[((1 * 2 + 0) * 16 + nt) * 64 + lane];
        short8v nEi1 = EFv[((1 * 2 + 1) * 16 + nt) * 64 + lane];
#pragma unroll
        for (int mtl = 0; mtl < 2; ++mtl) {
            int h0 = (wave * 2 + mtl) * 16;
            int hA = h0 + colp;
            int sw = (hA & 7) << 3;
            short8v Zr0 = *(const short8v*)&zs[hA * 64 + ((8 * rowq) ^ sw)];
            short8v Zr1 = *(const short8v*)&zs[hA * 64 + ((32 + 8 * rowq) ^ sw)];
            short8v Zi0 = *(const short8v*)&zs[16384 + hA * 64 + ((8 * rowq) ^ sw)];
            short8v Zi1 = *(const short8v*)&zs[16384 + hA * 64 + ((32 + 8 * rowq) ^ sw)];
            float4v acc = {0.f, 0.f, 0.f, 0.f};
            acc = __builtin_amdgcn_mfma_f32_16x16x32_bf16(Zr0, Er0,  acc, 0, 0, 0);
            acc = __builtin_amdgcn_mfma_f32_16x16x32_bf16(Zi0, nEi0, acc, 0, 0, 0);
            acc = __builtin_amdgcn_mfma_f32_16x16x32_bf16(Zr1, Er1,  acc, 0, 0, 0);
            acc = __builtin_amdgcn_mfma_f32_16x16x32_bf16(Zi1, nEi1, acc, 0, 0, 0);
            size_t ob = ((size_t)bo * 256 + h0 + rowq * 4) * 256 + nt * 16 + colp;
#pragma unroll
            for (int q = 0; q < 4; ++q)
                out[ob + (size_t)q * 256] = acc[q];
        }
    }
}

extern "C" void kernel_launch(void* const* d_in, const int* in_sizes, int n_in,
                              void* d_out, int out_size, void* d_ws, size_t ws_size,
                              hipStream_t stream) {
    const float* x  = (const float*)d_in[0];
    const float* a1 = (const float*)d_in[1];
    const float* b1 = (const float*)d_in[2];
    const float* c1 = (const float*)d_in[3];
    const float* d1 = (const float*)d_in[4];
    const float* a2 = (const float*)d_in[5];
    const float* b2 = (const float*)d_in[6];
    const float* c2 = (const float*)d_in[7];
    const float* d2 = (const float*)d_in[8];
    float* out = (float*)d_out;
    float* wsf = (float*)d_ws;

    if (ws_size < WS_FLOATS * sizeof(float)) return;

    unsigned short* Yt  = (unsigned short*)(wsf + oYT);
    float2*         XF  = (float2*)(wsf + oXF);
    float2*         OF  = (float2*)(wsf + oOF);
    unsigned short* BF  = (unsigned short*)(wsf + oBF);
    unsigned short* AF1 = (unsigned short*)(wsf + oAF1);
    unsigned short* AF2 = (unsigned short*)(wsf + oAF2);
    unsigned short* bA  = (unsigned short*)(wsf + oYT);  // after cmfma1, Yt region is dead
    unsigned short* gB  = bA + 1048576;
    unsigned short* tA  = (unsigned short*)(wsf + oTA);
    unsigned short* AFa = (unsigned short*)(wsf + oG);
    unsigned short* EF  = (unsigned short*)(wsf + oEF);

    k_prepTables<<<2304, 256, 0, stream>>>(a1, a2, AF1, AF2, BF, EF, AFa);
    k_stage1m<<<1024, 256, 0, stream>>>(x, BF, Yt);
    k_cmfma<256, 2><<<512, 256, 0, stream>>>(AF1, Yt, XF);
    k_prepBG<<<7168, 256, 0, stream>>>(b1, b2, c1, d1, c2, d2, bA, gB);
    k_contractA<<<512, 256, 0, stream>>>(XF, bA, gB, tA);
    k_amfma<<<512, 256, 0, stream>>>(AFa, tA, OF);
    k_ihinv<<<512, 512, 0, stream>>>(AF2, OF, EF, out);

    (void)in_sizes; (void)n_in; (void)out_size;
}

// Round 15
// 239.401 us; speedup vs baseline: 1.0897x; 1.0897x over previous
//
#include <hip/hip_runtime.h>
#include <math.h>

// FactorizedSpectralConv2d: pruned-DFT + TT contraction, MFMA everywhere matmul-shaped.
//
//   k_prepTables: split-bf16 A-frag tables FH/IH + FW B-frags + invW E B-frags + a A-frags
//   k_g         : g[r][j][x][y] = sum_k cc[j,x,k]*dc[k,y]  (G in then-dead OF region)
//   k_prepBG    : bf16 frag tables for b (A) and g (B) from G
//   k_stage1m   : W-DFT of x via MFMA -> Yt 4 bf16 planes [h/8][p][8] (LDS-staged twiddles)
//   k_cmfma     : XF[k][p] = sum_h FH[k][h] Yt[h][p]    (split-bf16 complex MFMA)
//   k_contractA : MFMA w-GEMM + fp32 t-update; t written as bf16-HI frag planes tA (2 planes)
//   k_amfma     : OF[o,(k,b,m)] = sum_i a[o,i] tA[i,(k,b,m)]  (a split, t hi-only; 8 MFMAs)
//   k_ihinv     : FUSED per-bo block: phase1 Z = IH·OF (OF split on the fly, Z -> LDS bf16-hi
//                 XOR-swizzled); phase2 out = Re(Z . E) via MFMA from LDS.

#define TWO_PI 6.28318530717958647692f

typedef __attribute__((ext_vector_type(8))) short short8v;   // 8 bf16 (4 VGPRs)
typedef __attribute__((ext_vector_type(4))) float float4v;   // MFMA C/D

namespace {
constexpr size_t P_ = 32768;            // B*C*KW pixel batch width

// workspace float offsets
constexpr size_t oYT = 0;                     // Yt: 4 planes [32][32768][8] bf16 = 16.77M floats
                                              //   then bA/gB + tA (contract)
constexpr size_t oTA = 1048576;               // tA: 2 planes [8][32768][8] bf16
constexpr size_t oXF = 16777216;              // XF f2 33.5MB
constexpr size_t oOF = 25165824;              // G f2 (2MB, until prepBG) then OF f2 33.5MB
constexpr size_t oBF = 33554432;              // FW B-frag table: 65536 shorts
constexpr size_t oAF1 = 33587200;             // FH frags: 196608 shorts
constexpr size_t oAF2 = 33685504;             // IH frags: 196608 shorts
constexpr size_t oG  = 33792000;              // AFa (98304 shorts) then EF (32768 shorts)
constexpr size_t oEF = oG + 262144;
constexpr size_t WS_FLOATS = oG + 524288;     // ~137.3 MB
}

__device__ __forceinline__ unsigned short f2bf(float f) {   // RNE float->bf16 bits
    unsigned int u = __float_as_uint(f);
    unsigned int r = (u + 0x7FFFu + ((u >> 16) & 1u)) >> 16;
    return (unsigned short)r;
}
__device__ __forceinline__ float bf2f(unsigned short b) {
    return __uint_as_float(((unsigned int)b) << 16);
}

// All static fragment tables in one launch.
__global__ __launch_bounds__(256) void k_prepTables(const float* __restrict__ a1,
                                                    const float* __restrict__ a2,
                                                    unsigned short* __restrict__ AF1,
                                                    unsigned short* __restrict__ AF2,
                                                    unsigned short* __restrict__ BF,
                                                    unsigned short* __restrict__ EF,
                                                    unsigned short* __restrict__ AFa) {
    int idx = blockIdx.x * 256 + threadIdx.x;      // < 589824
    if (idx < 393216) {
        int tbl = (idx >= 196608);
        int id = tbl ? (idx - 196608) : idx;
        int e = id & 7, lane = (id >> 3) & 63;
        int pl = id >> 15;
        float ang;
        if (!tbl) {
            int rt = (id >> 9) & 7, kc = (id >> 12) & 7;
            int r = rt * 16 + (lane & 15);             // k-row (128)
            int s = kc * 32 + 8 * (lane >> 4) + e;     // h (256)
            int kh = r + ((r >= 64) ? 128 : 0);
            int ph = (kh * s) & 255;
            ang = -TWO_PI * (float)ph / 256.0f;
        } else {
            int rt = (id >> 9) & 15, kc = (id >> 13) & 3;
            int r = rt * 16 + (lane & 15);             // h (256)
            int s = kc * 32 + 8 * (lane >> 4) + e;     // k (128)
            int kh = s + ((s >= 64) ? 128 : 0);
            int ph = (kh * r) & 255;
            ang = TWO_PI * (float)ph / 256.0f;
        }
        float sn, cs; sincosf(ang, &sn, &cs);
        float base = (pl < 2) ? cs : ((pl < 4) ? sn : -sn);
        unsigned short hi = f2bf(base);
        unsigned short out = (pl & 1) ? f2bf(base - bf2f(hi)) : hi;
        (tbl ? AF2 : AF1)[id] = out;
    } else if (idx < 458752) {
        int id = idx - 393216;                          // < 65536
        int e = id & 7, lane = (id >> 3) & 63;
        int nt = (id >> 9) & 3, kc = (id >> 11) & 7;
        int pl = id >> 14;                              // 0..3
        int kw = nt * 16 + (lane & 15);
        int w = kc * 32 + 8 * (lane >> 4) + e;
        int ph = (w * kw) & 255;
        float ang = -TWO_PI * (float)ph / 256.0f;
        float sn, cs; sincosf(ang, &sn, &cs);
        float base = (pl < 2) ? cs : sn;
        unsigned short hi = f2bf(base);
        unsigned short out = (pl & 1) ? f2bf(base - bf2f(hi)) : hi;
        BF[id] = out;
    } else if (idx < 491520) {
        int id = idx - 458752;                          // < 32768
        int e = id & 7, lane = (id >> 3) & 63;
        int nt = (id >> 9) & 15, kc = (id >> 13) & 1, pl = id >> 14;
        int w = nt * 16 + (lane & 15);
        int kw = kc * 32 + 8 * (lane >> 4) + e;
        int ph = (kw * w) & 255;
        float ang = TWO_PI * (float)ph / 256.0f;
        float sn, cs; sincosf(ang, &sn, &cs);
        float sc = ((kw == 0) ? 1.0f : 2.0f) / 65536.0f;
        float v = (pl == 0) ? (sc * cs) : (-sc * sn);
        EF[id] = f2bf(v);
    } else {
        int id = idx - 491520;                          // < 98304
        int e = id & 7, lane = (id >> 3) & 63;
        int rt = (id >> 9) & 7, kc = (id >> 12) & 1;
        int plreg = id >> 13;                           // 0..11
        int reg = plreg / 6, pl = plreg % 6;
        int o = rt * 16 + (lane & 15);
        int i = kc * 32 + 8 * (lane >> 4) + e;
        const float* ap = reg ? a2 : a1;
        float ar = ap[(o * 64 + i) * 2 + 0];
        float ai = ap[(o * 64 + i) * 2 + 1];
        float base = (pl < 2) ? ar : ((pl < 4) ? ai : -ai);
        unsigned short hi = f2bf(base);
        unsigned short out = (pl & 1) ? f2bf(base - bf2f(hi)) : hi;
        AFa[id] = out;
    }
}

// g[r][j][x][y] = sum_k cc[j,x,k] * dc[k,y]
__global__ __launch_bounds__(256) void k_g(const float* __restrict__ c1, const float* __restrict__ d1,
                                           const float* __restrict__ c2, const float* __restrict__ d2,
                                           float2* __restrict__ G) {
    int idx = blockIdx.x * 256 + threadIdx.x;      // < 262144
    int r = idx >> 17;
    int rem = idx & 131071;
    int j = rem >> 12;
    int xy = rem & 4095;
    int xm = xy >> 6, ym = xy & 63;
    const float* cp = r ? c2 : c1;
    const float* dp = r ? d2 : d1;
    float sr = 0.f, si = 0.f;
    for (int kk = 0; kk < 32; ++kk) {
        float cr = cp[((j * 64 + xm) * 32 + kk) * 2 + 0];
        float ci = cp[((j * 64 + xm) * 32 + kk) * 2 + 1];
        float dr = dp[(kk * 64 + ym) * 2 + 0];
        float di = dp[(kk * 64 + ym) * 2 + 1];
        sr = fmaf(cr, dr, fmaf(-ci, di, sr));
        si = fmaf(cr, di, fmaf( ci, dr, si));
    }
    G[(size_t)(r * 32 + j) * 4096 + xy] = make_float2(sr, si);
}

// bf16 fragment tables for the contraction (reads G).
__global__ __launch_bounds__(256) void k_prepBG(const float* __restrict__ b1, const float* __restrict__ b2,
                                                const float2* __restrict__ G,
                                                unsigned short* __restrict__ bA,
                                                unsigned short* __restrict__ gB) {
    size_t idx = (size_t)blockIdx.x * 256 + threadIdx.x;
    if (idx < 1048576) {
        int e     = idx & 7;
        int lane  = (idx >> 3) & 63;
        int c     = (idx >> 9) & 127;
        int itile = (idx >> 16) & 3;
        int reg   = (idx >> 18) & 1;
        int plane = (idx >> 19) & 1;
        int i = itile * 16 + (lane & 15);
        int j = 8 * (lane >> 4) + e;
        const float* bp = reg ? b2 : b1;
        float v = bp[((size_t)(i * 128 + c) * 32 + j) * 2 + plane];
        bA[idx] = f2bf(v);
    } else if (idx < 1048576 + 786432) {
        size_t i2 = idx - 1048576;
        int e     = i2 & 7;
        int lane  = (i2 >> 3) & 63;
        int ytile = (i2 >> 9) & 3;
        int x     = (i2 >> 11) & 63;
        int reg   = (i2 >> 17) & 1;
        int plane = (int)(i2 >> 18);           // 0,1,2
        int y = ytile * 16 + (lane & 15);
        int j = 8 * (lane >> 4) + e;
        float2 gv = G[(size_t)(reg * 32 + j) * 4096 + x * 64 + y];
        float v = (plane == 0) ? gv.x : ((plane == 1) ? gv.y : -gv.y);
        gB[i2] = f2bf(v);
    }
}

// MFMA W-DFT v4: BF staged via LDS in 32KB barrier-synced phases (2 kc each).
__global__ __launch_bounds__(256) void k_stage1m(const float* __restrict__ x,
                                                 const unsigned short* __restrict__ BF,
                                                 unsigned short* __restrict__ Yt) {
    __shared__ __align__(16) unsigned short es[16384];   // 32 KB
    int t = threadIdx.x;
    int wave = t >> 6, lane = t & 63;
    size_t row0 = (size_t)blockIdx.x * 128 + (size_t)wave * 32;
    int colp = lane & 15, rowq = lane >> 4;
    const short8v* esv = (const short8v*)es;

    float4v accR[2][4], accI[2][4];
#pragma unroll
    for (int rt = 0; rt < 2; ++rt)
#pragma unroll
        for (int nt = 0; nt < 4; ++nt) {
            accR[rt][nt] = (float4v){0.f, 0.f, 0.f, 0.f};
            accI[rt][nt] = (float4v){0.f, 0.f, 0.f, 0.f};
        }

    const float* xb0 = x + (row0 + colp) * 256 + 8 * rowq;
    const float* xb1 = xb0 + 16 * 256;
    float4 nv[2][2];
    nv[0][0] = *(const float4*)(xb0);  nv[0][1] = *(const float4*)(xb0 + 4);
    nv[1][0] = *(const float4*)(xb1);  nv[1][1] = *(const float4*)(xb1 + 4);

    const float4* bf4 = (const float4*)BF;
    for (int ph = 0; ph < 4; ++ph) {
        __syncthreads();
        {
#pragma unroll
            for (int i = 0; i < 8; ++i) {
                int idx = t + 256 * i;
                int li  = idx & 63;
                int nt  = (idx >> 6) & 3;
                int kcl = (idx >> 8) & 1;
                int pl  = idx >> 9;
                ((float4*)es)[idx] = bf4[((size_t)(pl * 8 + ph * 2 + kcl) * 4 + nt) * 64 + li];
            }
        }
        __syncthreads();
        for (int kcl = 0; kcl < 2; ++kcl) {
            int kc = ph * 2 + kcl;
            short8v xh[2];
#pragma unroll
            for (int rt = 0; rt < 2; ++rt) {
                float4 v0 = nv[rt][0], v1 = nv[rt][1];
                float vv[8] = {v0.x, v0.y, v0.z, v0.w, v1.x, v1.y, v1.z, v1.w};
#pragma unroll
                for (int j = 0; j < 8; ++j) xh[rt][j] = (short)f2bf(vv[j]);
            }
            if (kc < 7) {
                nv[0][0] = *(const float4*)(xb0 + (kc + 1) * 32);
                nv[0][1] = *(const float4*)(xb0 + (kc + 1) * 32 + 4);
                nv[1][0] = *(const float4*)(xb1 + (kc + 1) * 32);
                nv[1][1] = *(const float4*)(xb1 + (kc + 1) * 32 + 4);
            }
#pragma unroll
            for (int nt = 0; nt < 4; ++nt) {
                short8v Bch = esv[((0 * 2 + kcl) * 4 + nt) * 64 + lane];
                short8v Bcl = esv[((1 * 2 + kcl) * 4 + nt) * 64 + lane];
                short8v Bsh = esv[((2 * 2 + kcl) * 4 + nt) * 64 + lane];
                short8v Bsl = esv[((3 * 2 + kcl) * 4 + nt) * 64 + lane];
#pragma unroll
                for (int rt = 0; rt < 2; ++rt) {
                    float4v r_ = accR[rt][nt];
                    r_ = __builtin_amdgcn_mfma_f32_16x16x32_bf16(xh[rt], Bch, r_, 0, 0, 0);
                    r_ = __builtin_amdgcn_mfma_f32_16x16x32_bf16(xh[rt], Bcl, r_, 0, 0, 0);
                    accR[rt][nt] = r_;
                    float4v i_ = accI[rt][nt];
                    i_ = __builtin_amdgcn_mfma_f32_16x16x32_bf16(xh[rt], Bsh, i_, 0, 0, 0);
                    i_ = __builtin_amdgcn_mfma_f32_16x16x32_bf16(xh[rt], Bsl, i_, 0, 0, 0);
                    accI[rt][nt] = i_;
                }
            }
        }
    }

    short* Yts = (short*)Yt;
    const size_t PLY = (size_t)32 * 32768 * 8;
#pragma unroll
    for (int rt = 0; rt < 2; ++rt) {
        size_t xrow0 = row0 + rt * 16 + rowq * 4;
        int h = (int)(xrow0 & 255), bc = (int)(xrow0 >> 8);
        size_t gbase = (size_t)(h >> 3) * 32768;
        int e0 = h & 7;
#pragma unroll
        for (int nt = 0; nt < 4; ++nt) {
            size_t p = (size_t)bc * 64 + nt * 16 + colp;
            size_t off = (gbase + p) * 8 + e0;
            float4v R = accR[rt][nt], I = accI[rt][nt];
            short rh[4], rl[4], ih[4], il[4];
#pragma unroll
            for (int q = 0; q < 4; ++q) {
                unsigned short h1 = f2bf(R[q]);
                rh[q] = (short)h1; rl[q] = (short)f2bf(R[q] - bf2f(h1));
                unsigned short h2 = f2bf(I[q]);
                ih[q] = (short)h2; il[q] = (short)f2bf(I[q] - bf2f(h2));
            }
            *(short4*)&Yts[0 * PLY + off] = make_short4(rh[0], rh[1], rh[2], rh[3]);
            *(short4*)&Yts[1 * PLY + off] = make_short4(rl[0], rl[1], rl[2], rl[3]);
            *(short4*)&Yts[2 * PLY + off] = make_short4(ih[0], ih[1], ih[2], ih[3]);
            *(short4*)&Yts[3 * PLY + off] = make_short4(il[0], il[1], il[2], il[3]);
        }
    }
}

// Split-bf16 complex MFMA GEMM (FH: Yt -> XF).
template<int S, int RT_W>
__global__ __launch_bounds__(256) void k_cmfma(const unsigned short* __restrict__ AF,
                                               const unsigned short* __restrict__ Bt,
                                               float2* __restrict__ Out) {
    constexpr int KC = S / 32;
    constexpr int SG = S / 8;
    constexpr int RTOT = RT_W * 4;
    __shared__ __align__(16) unsigned short bs[4 * SG * 16 * 8];
    int t = threadIdx.x;
    int wave = t >> 6, lane = t & 63;
    int rt0 = wave * RT_W;
    int colp = lane & 15, rowq = lane >> 4;
    const short8v* AFv = (const short8v*)AF;
    const short8v* bsv = (const short8v*)bs;
    const size_t PLA = (size_t)KC * RTOT * 64;

    for (int pt = 0; pt < 4; ++pt) {
        int p0 = blockIdx.x * 64 + pt * 16;
        __syncthreads();
        {
            const float4* src = (const float4*)Bt;
            float4* dst = (float4*)bs;
            for (int e = t; e < 4 * SG * 16; e += 256) {
                int pl = e / (SG * 16); int rem = e - pl * (SG * 16);
                int g = rem >> 4, li = rem & 15;
                dst[e] = src[((size_t)pl * SG + g) * 32768 + p0 + li];
            }
        }
        __syncthreads();
        float4v accR[RT_W], accI[RT_W];
#pragma unroll
        for (int rt = 0; rt < RT_W; ++rt) {
            accR[rt] = (float4v){0.f, 0.f, 0.f, 0.f};
            accI[rt] = (float4v){0.f, 0.f, 0.f, 0.f};
        }
#pragma unroll
        for (int kc = 0; kc < KC; ++kc) {
            int gi = kc * 4 + rowq;
            short8v Brh = bsv[((0 * SG + gi) << 4) + colp];
            short8v Brl = bsv[((1 * SG + gi) << 4) + colp];
            short8v Bih = bsv[((2 * SG + gi) << 4) + colp];
            short8v Bil = bsv[((3 * SG + gi) << 4) + colp];
#pragma unroll
            for (int rt = 0; rt < RT_W; ++rt) {
                size_t ab = ((size_t)kc * RTOT + rt0 + rt) * 64 + lane;
                short8v A0 = AFv[0 * PLA + ab];
                short8v A1 = AFv[1 * PLA + ab];
                short8v A2 = AFv[2 * PLA + ab];
                short8v A3 = AFv[3 * PLA + ab];
                short8v A4 = AFv[4 * PLA + ab];
                short8v A5 = AFv[5 * PLA + ab];
                float4v r_ = accR[rt];
                r_ = __builtin_amdgcn_mfma_f32_16x16x32_bf16(A0, Brh, r_, 0, 0, 0);
                r_ = __builtin_amdgcn_mfma_f32_16x16x32_bf16(A0, Brl, r_, 0, 0, 0);
                r_ = __builtin_amdgcn_mfma_f32_16x16x32_bf16(A1, Brh, r_, 0, 0, 0);
                r_ = __builtin_amdgcn_mfma_f32_16x16x32_bf16(A4, Bih, r_, 0, 0, 0);
                r_ = __builtin_amdgcn_mfma_f32_16x16x32_bf16(A4, Bil, r_, 0, 0, 0);
                r_ = __builtin_amdgcn_mfma_f32_16x16x32_bf16(A5, Bih, r_, 0, 0, 0);
                accR[rt] = r_;
                float4v i_ = accI[rt];
                i_ = __builtin_amdgcn_mfma_f32_16x16x32_bf16(A2, Brh, i_, 0, 0, 0);
                i_ = __builtin_amdgcn_mfma_f32_16x16x32_bf16(A2, Brl, i_, 0, 0, 0);
                i_ = __builtin_amdgcn_mfma_f32_16x16x32_bf16(A3, Brh, i_, 0, 0, 0);
                i_ = __builtin_amdgcn_mfma_f32_16x16x32_bf16(A0, Bih, i_, 0, 0, 0);
                i_ = __builtin_amdgcn_mfma_f32_16x16x32_bf16(A0, Bil, i_, 0, 0, 0);
                i_ = __builtin_amdgcn_mfma_f32_16x16x32_bf16(A1, Bih, i_, 0, 0, 0);
                accI[rt] = i_;
            }
        }
#pragma unroll
        for (int rt = 0; rt < RT_W; ++rt) {
            int rbase = (rt0 + rt) * 16 + rowq * 4;
#pragma unroll
            for (int q = 0; q < 4; ++q)
                Out[(size_t)(rbase + q) * P_ + p0 + colp] = make_float2(accR[rt][q], accI[rt][q]);
        }
    }
}

// MFMA contract, phase A -> tA bf16-HI only (2 planes).
__global__ __launch_bounds__(256) void k_contractA(const float2* __restrict__ XF,
                                                   const unsigned short* __restrict__ bA,
                                                   const unsigned short* __restrict__ gB,
                                                   unsigned short* __restrict__ tA) {
    int t = threadIdx.x;
    int k = blockIdx.x >> 2;
    int ytile = blockIdx.x & 3;
    int y0 = ytile << 4;
    int reg = (k >= 64) ? 1 : 0;
    int x = k & 63;
    int itile = t >> 6, lane = t & 63;
    int ylane = lane & 15, qg = lane >> 4;

    const short8v* gBv = (const short8v*)gB;
    short8v g_r  = gBv[(((size_t)(0 * 2 + reg) * 64 + x) * 4 + ytile) * 64 + lane];
    short8v g_i  = gBv[(((size_t)(1 * 2 + reg) * 64 + x) * 4 + ytile) * 64 + lane];
    short8v g_ni = gBv[(((size_t)(2 * 2 + reg) * 64 + x) * 4 + ytile) * 64 + lane];

    const short8v* bAv = (const short8v*)bA;
    size_t aR = (((size_t)(0 * 2 + reg) * 4 + itile) * 128) * 64 + lane;
    size_t aI = (((size_t)(1 * 2 + reg) * 4 + itile) * 128) * 64 + lane;

    const float2* xfp = XF + (size_t)k * 32768 + y0 + ylane;

    float tr[4][4], ti[4][4];
#pragma unroll
    for (int q = 0; q < 4; ++q)
#pragma unroll
        for (int b = 0; b < 4; ++b) { tr[q][b] = 0.f; ti[q][b] = 0.f; }

#pragma unroll 2
    for (int c = 0; c < 128; ++c) {
        short8v av = bAv[aR + (size_t)c * 64];
        short8v aw = bAv[aI + (size_t)c * 64];
        float4v z4 = {0.f, 0.f, 0.f, 0.f};
        float4v wr = __builtin_amdgcn_mfma_f32_16x16x32_bf16(av, g_r, z4, 0, 0, 0);
        wr = __builtin_amdgcn_mfma_f32_16x16x32_bf16(aw, g_ni, wr, 0, 0, 0);
        float4v wi = __builtin_amdgcn_mfma_f32_16x16x32_bf16(av, g_i, z4, 0, 0, 0);
        wi = __builtin_amdgcn_mfma_f32_16x16x32_bf16(aw, g_r, wi, 0, 0, 0);
#pragma unroll
        for (int b = 0; b < 4; ++b) {
            float2 xv = xfp[(size_t)b * 8192 + (size_t)c * 64];
#pragma unroll
            for (int q = 0; q < 4; ++q) {
                tr[q][b] = fmaf(wr[q], xv.x, fmaf(-wi[q], xv.y, tr[q][b]));
                ti[q][b] = fmaf(wr[q], xv.y, fmaf( wi[q], xv.x, ti[q][b]));
            }
        }
    }

    short* tAs = (short*)tA;
    const size_t PLT = (size_t)8 * 32768 * 8;     // plane stride (shorts)
    int gidx = itile * 2 + (qg >> 1);
    int e0 = (qg & 1) * 4;
#pragma unroll
    for (int b = 0; b < 4; ++b) {
        size_t col = (size_t)k * 256 + (size_t)b * 64 + y0 + ylane;
        size_t off = ((size_t)gidx * 32768 + col) * 8 + e0;
        short rh[4], ih[4];
#pragma unroll
        for (int q = 0; q < 4; ++q) {
            rh[q] = (short)f2bf(tr[q][b]);
            ih[q] = (short)f2bf(ti[q][b]);
        }
        *(short4*)&tAs[0 * PLT + off] = make_short4(rh[0], rh[1], rh[2], rh[3]);
        *(short4*)&tAs[1 * PLT + off] = make_short4(ih[0], ih[1], ih[2], ih[3]);
    }
}

// MFMA contract, phase B -> OF fp32. (a split-bf16, t bf16-hi: 8 MFMAs per (kc,rt))
__global__ __launch_bounds__(256) void k_amfma(const unsigned short* __restrict__ AFa,
                                               const unsigned short* __restrict__ tA,
                                               float2* __restrict__ OF) {
    constexpr int SG = 8;
    __shared__ __align__(16) unsigned short bs[2 * SG * 16 * 8];   // 4 KB
    int t = threadIdx.x;
    int wave = t >> 6, lane = t & 63;
    int rt0 = wave * 2;
    int colp = lane & 15, rowq = lane >> 4;
    int k = blockIdx.x >> 2, b = blockIdx.x & 3;
    int reg = (k >= 64) ? 1 : 0;
    const short8v* AFv = (const short8v*)(AFa + (size_t)reg * 6 * 2 * 8 * 512);
    const size_t PLA = 2 * 8 * 64;
    const short8v* bsv = (const short8v*)bs;
    size_t p0 = (size_t)blockIdx.x * 64;

    for (int pt = 0; pt < 4; ++pt) {
        __syncthreads();
        {   // stage 2 planes x 8 groups x 16 cols = 256 float4 (1/thread)
            const float4* src = (const float4*)tA;
            float4* dst = (float4*)bs;
            int e = t;
            int pl = e >> 7; int rem = e & 127;
            int g = rem >> 4, li = rem & 15;
            dst[e] = src[((size_t)pl * SG + g) * 32768 + p0 + pt * 16 + li];
        }
        __syncthreads();
        float4v accR[2], accI[2];
#pragma unroll
        for (int rt = 0; rt < 2; ++rt) {
            accR[rt] = (float4v){0.f, 0.f, 0.f, 0.f};
            accI[rt] = (float4v){0.f, 0.f, 0.f, 0.f};
        }
#pragma unroll
        for (int kc = 0; kc < 2; ++kc) {
            int gi = kc * 4 + rowq;
            short8v Brh = bsv[((0 * SG + gi) << 4) + colp];
            short8v Bih = bsv[((1 * SG + gi) << 4) + colp];
#pragma unroll
            for (int rt = 0; rt < 2; ++rt) {
                size_t ab = ((size_t)kc * 8 + rt0 + rt) * 64 + lane;
                short8v A0 = AFv[0 * PLA + ab];
                short8v A1 = AFv[1 * PLA + ab];
                short8v A2 = AFv[2 * PLA + ab];
                short8v A3 = AFv[3 * PLA + ab];
                short8v A4 = AFv[4 * PLA + ab];
                short8v A5 = AFv[5 * PLA + ab];
                float4v r_ = accR[rt];
                r_ = __builtin_amdgcn_mfma_f32_16x16x32_bf16(A0, Brh, r_, 0, 0, 0);
                r_ = __builtin_amdgcn_mfma_f32_16x16x32_bf16(A1, Brh, r_, 0, 0, 0);
                r_ = __builtin_amdgcn_mfma_f32_16x16x32_bf16(A4, Bih, r_, 0, 0, 0);
                r_ = __builtin_amdgcn_mfma_f32_16x16x32_bf16(A5, Bih, r_, 0, 0, 0);
                accR[rt] = r_;
                float4v i_ = accI[rt];
                i_ = __builtin_amdgcn_mfma_f32_16x16x32_bf16(A2, Brh, i_, 0, 0, 0);
                i_ = __builtin_amdgcn_mfma_f32_16x16x32_bf16(A3, Brh, i_, 0, 0, 0);
                i_ = __builtin_amdgcn_mfma_f32_16x16x32_bf16(A0, Bih, i_, 0, 0, 0);
                i_ = __builtin_amdgcn_mfma_f32_16x16x32_bf16(A1, Bih, i_, 0, 0, 0);
                accI[rt] = i_;
            }
        }
        int m = pt * 16 + colp;
#pragma unroll
        for (int rt = 0; rt < 2; ++rt) {
            int o0 = (rt0 + rt) * 16 + rowq * 4;
#pragma unroll
            for (int q = 0; q < 4; ++q)
                OF[(size_t)k * 32768 + (size_t)b * 8192 + (size_t)(o0 + q) * 64 + m] =
                    make_float2(accR[rt][q], accI[rt][q]);
        }
    }
}

// FUSED IH-GEMM + inverse-W MFMA. Block = one bo (b*128+o), 512 threads (8 waves).
__global__ __launch_bounds__(512) void k_ihinv(const unsigned short* __restrict__ AF2,
                                               const float2* __restrict__ OF,
                                               const unsigned short* __restrict__ EF,
                                               float* __restrict__ out) {
    constexpr int SG = 16, KC = 4, RTOT = 16;
    __shared__ __align__(16) unsigned short zs[2 * 256 * 64];     // 64 KB
    __shared__ __align__(16) unsigned short bs[4 * SG * 16 * 8];  // 16 KB
    int t = threadIdx.x;
    int wave = t >> 6, lane = t & 63;
    int colp = lane & 15, rowq = lane >> 4;
    int rt0 = wave * 2;
    int bo = blockIdx.x;
    size_t p0 = (size_t)bo * 64;
    const short8v* AFv = (const short8v*)AF2;
    const short8v* bsv = (const short8v*)bs;
    const size_t PLA = (size_t)KC * RTOT * 64;

    for (int pt = 0; pt < 4; ++pt) {
        __syncthreads();
        {   // stage B tile from OF fp32 (split hi/lo): 512 threads x 4 rows each
            int li = t & 15, g = (t >> 4) & 15, half = t >> 8;
            int e0 = half * 4;
            short rh[4], rl[4], ih[4], il[4];
#pragma unroll
            for (int j = 0; j < 4; ++j) {
                float2 v = OF[(size_t)(g * 8 + e0 + j) * P_ + p0 + pt * 16 + li];
                unsigned short h1 = f2bf(v.x);
                rh[j] = (short)h1; rl[j] = (short)f2bf(v.x - bf2f(h1));
                unsigned short h2 = f2bf(v.y);
                ih[j] = (short)h2; il[j] = (short)f2bf(v.y - bf2f(h2));
            }
            int base = (g * 16 + li) * 8 + e0;
            *(short4*)&bs[0 * 2048 + base] = make_short4(rh[0], rh[1], rh[2], rh[3]);
            *(short4*)&bs[1 * 2048 + base] = make_short4(rl[0], rl[1], rl[2], rl[3]);
            *(short4*)&bs[2 * 2048 + base] = make_short4(ih[0], ih[1], ih[2], ih[3]);
            *(short4*)&bs[3 * 2048 + base] = make_short4(il[0], il[1], il[2], il[3]);
        }
        __syncthreads();
        float4v accR[2], accI[2];
#pragma unroll
        for (int rt = 0; rt < 2; ++rt) {
            accR[rt] = (float4v){0.f, 0.f, 0.f, 0.f};
            accI[rt] = (float4v){0.f, 0.f, 0.f, 0.f};
        }
#pragma unroll
        for (int kc = 0; kc < KC; ++kc) {
            int gi = kc * 4 + rowq;
            short8v Brh = bsv[((0 * SG + gi) << 4) + colp];
            short8v Brl = bsv[((1 * SG + gi) << 4) + colp];
            short8v Bih = bsv[((2 * SG + gi) << 4) + colp];
            short8v Bil = bsv[((3 * SG + gi) << 4) + colp];
#pragma unroll
            for (int rt = 0; rt < 2; ++rt) {
                size_t ab = ((size_t)kc * RTOT + rt0 + rt) * 64 + lane;
                short8v A0 = AFv[0 * PLA + ab];
                short8v A1 = AFv[1 * PLA + ab];
                short8v A2 = AFv[2 * PLA + ab];
                short8v A3 = AFv[3 * PLA + ab];
                short8v A4 = AFv[4 * PLA + ab];
                short8v A5 = AFv[5 * PLA + ab];
                float4v r_ = accR[rt];
                r_ = __builtin_amdgcn_mfma_f32_16x16x32_bf16(A0, Brh, r_, 0, 0, 0);
                r_ = __builtin_amdgcn_mfma_f32_16x16x32_bf16(A0, Brl, r_, 0, 0, 0);
                r_ = __builtin_amdgcn_mfma_f32_16x16x32_bf16(A1, Brh, r_, 0, 0, 0);
                r_ = __builtin_amdgcn_mfma_f32_16x16x32_bf16(A4, Bih, r_, 0, 0, 0);
                r_ = __builtin_amdgcn_mfma_f32_16x16x32_bf16(A4, Bil, r_, 0, 0, 0);
                r_ = __builtin_amdgcn_mfma_f32_16x16x32_bf16(A5, Bih, r_, 0, 0, 0);
                accR[rt] = r_;
                float4v i_ = accI[rt];
                i_ = __builtin_amdgcn_mfma_f32_16x16x32_bf16(A2, Brh, i_, 0, 0, 0);
                i_ = __builtin_amdgcn_mfma_f32_16x16x32_bf16(A2, Brl, i_, 0, 0, 0);
                i_ = __builtin_amdgcn_mfma_f32_16x16x32_bf16(A3, Brh, i_, 0, 0, 0);
                i_ = __builtin_amdgcn_mfma_f32_16x16x32_bf16(A0, Bih, i_, 0, 0, 0);
                i_ = __builtin_amdgcn_mfma_f32_16x16x32_bf16(A0, Bil, i_, 0, 0, 0);
                i_ = __builtin_amdgcn_mfma_f32_16x16x32_bf16(A1, Bih, i_, 0, 0, 0);
                accI[rt] = i_;
            }
        }
#pragma unroll
        for (int rt = 0; rt < 2; ++rt)
#pragma unroll
            for (int q = 0; q < 4; ++q) {
                int h = (rt0 + rt) * 16 + rowq * 4 + q;
                int kwsw = (pt * 16 + colp) ^ ((h & 7) << 3);
                zs[h * 64 + kwsw] = (unsigned short)f2bf(accR[rt][q]);
                zs[16384 + h * 64 + kwsw] = (unsigned short)f2bf(accI[rt][q]);
            }
    }
    __syncthreads();

    const short8v* EFv = (const short8v*)EF;
    for (int nt = 0; nt < 16; ++nt) {
        short8v Er0  = EFv[((0 * 2 + 0) * 16 + nt) * 64 + lane];
        short8v Er1  = EFv[((0 * 2 + 1) * 16 + nt) * 64 + lane];
        short8v nEi0 = EFv[((1 * 2 + 0) * 16 + nt) * 64 + lane];
        short8v nEi1 = EFv[((1 * 2 + 1) * 16 + nt) * 64 + lane];
#pragma unroll
        for (int mtl = 0; mtl < 2; ++mtl) {
            int h0 = (wave * 2 + mtl) * 16;
            int hA = h0 + colp;
            int sw = (hA & 7) << 3;
            short8v Zr0 = *(const short8v*)&zs[hA * 64 + ((8 * rowq) ^ sw)];
            short8v Zr1 = *(const short8v*)&zs[hA * 64 + ((32 + 8 * rowq) ^ sw)];
            short8v Zi0 = *(const short8v*)&zs[16384 + hA * 64 + ((8 * rowq) ^ sw)];
            short8v Zi1 = *(const short8v*)&zs[16384 + hA * 64 + ((32 + 8 * rowq) ^ sw)];
            float4v acc = {0.f, 0.f, 0.f, 0.f};
            acc = __builtin_amdgcn_mfma_f32_16x16x32_bf16(Zr0, Er0,  acc, 0, 0, 0);
            acc = __builtin_amdgcn_mfma_f32_16x16x32_bf16(Zi0, nEi0, acc, 0, 0, 0);
            acc = __builtin_amdgcn_mfma_f32_16x16x32_bf16(Zr1, Er1,  acc, 0, 0, 0);
            acc = __builtin_amdgcn_mfma_f32_16x16x32_bf16(Zi1, nEi1, acc, 0, 0, 0);
            size_t ob = ((size_t)bo * 256 + h0 + rowq * 4) * 256 + nt * 16 + colp;
#pragma unroll
            for (int q = 0; q < 4; ++q)
                out[ob + (size_t)q * 256] = acc[q];
        }
    }
}

extern "C" void kernel_launch(void* const* d_in, const int* in_sizes, int n_in,
                              void* d_out, int out_size, void* d_ws, size_t ws_size,
                              hipStream_t stream) {
    const float* x  = (const float*)d_in[0];
    const float* a1 = (const float*)d_in[1];
    const float* b1 = (const float*)d_in[2];
    const float* c1 = (const float*)d_in[3];
    const float* d1 = (const float*)d_in[4];
    const float* a2 = (const float*)d_in[5];
    const float* b2 = (const float*)d_in[6];
    const float* c2 = (const float*)d_in[7];
    const float* d2 = (const float*)d_in[8];
    float* out = (float*)d_out;
    float* wsf = (float*)d_ws;

    if (ws_size < WS_FLOATS * sizeof(float)) return;

    unsigned short* Yt  = (unsigned short*)(wsf + oYT);
    float2*         XF  = (float2*)(wsf + oXF);
    float2*         OF  = (float2*)(wsf + oOF);
    float2*         G   = (float2*)(wsf + oOF);          // G lives in OF region until prepBG
    unsigned short* BF  = (unsigned short*)(wsf + oBF);
    unsigned short* AF1 = (unsigned short*)(wsf + oAF1);
    unsigned short* AF2 = (unsigned short*)(wsf + oAF2);
    unsigned short* bA  = (unsigned short*)(wsf + oYT);  // after cmfma1, Yt region is dead
    unsigned short* gB  = bA + 1048576;
    unsigned short* tA  = (unsigned short*)(wsf + oTA);
    unsigned short* AFa = (unsigned short*)(wsf + oG);
    unsigned short* EF  = (unsigned short*)(wsf + oEF);

    k_prepTables<<<2304, 256, 0, stream>>>(a1, a2, AF1, AF2, BF, EF, AFa);
    k_g<<<1024, 256, 0, stream>>>(c1, d1, c2, d2, G);
    k_stage1m<<<1024, 256, 0, stream>>>(x, BF, Yt);
    k_cmfma<256, 2><<<512, 256, 0, stream>>>(AF1, Yt, XF);
    k_prepBG<<<7168, 256, 0, stream>>>(b1, b2, G, bA, gB);
    k_contractA<<<512, 256, 0, stream>>>(XF, bA, gB, tA);
    k_amfma<<<512, 256, 0, stream>>>(AFa, tA, OF);       // overwrites G (dead after prepBG)
    k_ihinv<<<512, 512, 0, stream>>>(AF2, OF, EF, out);

    (void)in_sizes; (void)n_in; (void)out_size;
}